// Round 3
// baseline (248.834 us; speedup 1.0000x reference)
//
#include <hip/hip_runtime.h>
#include <math.h>

#define NUM_E 8
#define DIM 4096
#define THREADS 256
#define WAVES (THREADS / 64)
#define VEC_ITERS (DIM / (THREADS * 4))   // 4
#define ROWS 4

typedef float f32x4 __attribute__((ext_vector_type(4)));

__device__ __forceinline__ f32x4 nt_load4(const float* p) {
    return __builtin_nontemporal_load(reinterpret_cast<const f32x4*>(p));
}
__device__ __forceinline__ void nt_store4(float* p, f32x4 v) {
    __builtin_nontemporal_store(v, reinterpret_cast<f32x4*>(p));
}

__global__ __launch_bounds__(THREADS) void gate_fused_kernel(
    const float* __restrict__ x,        // [B, D]
    const float* __restrict__ experts,  // [B, NUM, D]
    const float* __restrict__ W,        // [NUM, D]
    float* __restrict__ out)            // [B, D]
{
    const int b0   = blockIdx.x * ROWS;
    const int t    = threadIdx.x;
    const int lane = t & 63;
    const int wave = t >> 6;

    // reduced partial logits: [row][wave][expert]
    __shared__ float red[ROWS][WAVES][NUM_E];

    // ---- Phase 1: partial dot products x[b,:] . W[n,:] for ROWS rows ----
#pragma unroll
    for (int r = 0; r < ROWS; ++r) {
        const float* __restrict__ xrow = x + (size_t)(b0 + r) * DIM;
        float p[NUM_E];
#pragma unroll
        for (int n = 0; n < NUM_E; ++n) p[n] = 0.0f;

#pragma unroll
        for (int i = 0; i < VEC_ITERS; ++i) {
            const int d = (i * THREADS + t) * 4;
            const f32x4 xv = nt_load4(xrow + d);
#pragma unroll
            for (int n = 0; n < NUM_E; ++n) {
                const f32x4 wv = *reinterpret_cast<const f32x4*>(W + n * DIM + d);
                p[n] += xv.x * wv.x + xv.y * wv.y + xv.z * wv.z + xv.w * wv.w;
            }
        }

        // wave-level butterfly reduce (64 lanes)
#pragma unroll
        for (int n = 0; n < NUM_E; ++n) {
#pragma unroll
            for (int off = 32; off > 0; off >>= 1)
                p[n] += __shfl_down(p[n], off, 64);
        }
        if (lane == 0) {
#pragma unroll
            for (int n = 0; n < NUM_E; ++n) red[r][wave][n] = p[n];
        }
    }
    __syncthreads();

    // ---- Phase 2: softmax (redundant per thread, 8-wide) + weighted combine ----
#pragma unroll
    for (int r = 0; r < ROWS; ++r) {
        float wgt[NUM_E];
#pragma unroll
        for (int n = 0; n < NUM_E; ++n) {
            float s = 0.0f;
#pragma unroll
            for (int w2 = 0; w2 < WAVES; ++w2) s += red[r][w2][n];
            wgt[n] = s;
        }
        float m = wgt[0];
#pragma unroll
        for (int n = 1; n < NUM_E; ++n) m = fmaxf(m, wgt[n]);
        float sum = 0.0f;
#pragma unroll
        for (int n = 0; n < NUM_E; ++n) {
            wgt[n] = __expf(wgt[n] - m);
            sum += wgt[n];
        }
        const float inv = 1.0f / sum;
#pragma unroll
        for (int n = 0; n < NUM_E; ++n) wgt[n] *= inv;

        const float* __restrict__ erow = experts + (size_t)(b0 + r) * NUM_E * DIM;
        float* __restrict__ orow = out + (size_t)(b0 + r) * DIM;

#pragma unroll
        for (int i = 0; i < VEC_ITERS; ++i) {
            const int d = (i * THREADS + t) * 4;
            f32x4 acc = (f32x4)(0.0f);
#pragma unroll
            for (int n = 0; n < NUM_E; ++n) {
                const f32x4 ev = nt_load4(erow + (size_t)n * DIM + d);
                acc.x += wgt[n] * ev.x;
                acc.y += wgt[n] * ev.y;
                acc.z += wgt[n] * ev.z;
                acc.w += wgt[n] * ev.w;
            }
            nt_store4(orow + d, acc);
        }
    }
}

extern "C" void kernel_launch(void* const* d_in, const int* in_sizes, int n_in,
                              void* d_out, int out_size, void* d_ws, size_t ws_size,
                              hipStream_t stream) {
    const float* x       = (const float*)d_in[0];
    const float* experts = (const float*)d_in[1];
    const float* W       = (const float*)d_in[2];
    float* out           = (float*)d_out;

    const int B = in_sizes[0] / DIM;   // 8192

    gate_fused_kernel<<<B / ROWS, THREADS, 0, stream>>>(x, experts, W, out);
}